// Round 6
// baseline (1043.376 us; speedup 1.0000x reference)
//
#include <hip/hip_runtime.h>
#include <hip/hip_bf16.h>

#define B_ 32
#define P_ 512
#define Q_ 64
#define E_ 300
#define KP 320          // E padded to multiple of 32 for MFMA K-steps
#define H_ 256
#define HH_ 128
#define NEG (-1e7f)
#define BP (B_*P_)
#define BQ (B_*Q_)

typedef __attribute__((ext_vector_type(8))) short bf16x8;
typedef __attribute__((ext_vector_type(4))) float f32x4;

// ---- static device workspace (fully rewritten every call) ----
__device__ __hip_bfloat16 g_ep[BP][KP];      // gathered passage embeddings (bf16)
__device__ __hip_bfloat16 g_eq[BQ][KP];      // gathered question embeddings
__device__ __hip_bfloat16 g_wp[768][KP];     // combined passage wih
__device__ __hip_bfloat16 g_wq[768][KP];     // combined question wih
__device__ float g_biasp[768];               // bih (+ bhh for r,z gates)
__device__ float g_biasq[768];
__device__ float g_biasn[4][HH_];            // bhh n-gate bias per weight set
__device__ short g_whhrep[4*12*512*8];       // whh repacked in MFMA B-frag order
__device__ float g_xtp[2L*P_*B_*384];        // passage x-proj, [dir][t][b][384]
__device__ float g_xtq[2L*Q_*B_*384];        // question x-proj
__device__ float g_penc[BP*H_];              // BiGRU passage encodings (f32)
__device__ float g_qenc[BQ*H_];              // BiGRU question encodings

struct PrepArgs { const float* wih[4]; const float* bih[4]; const float* bhh[4]; };

// ---------------- weight repack + bias fold ----------------
__global__ __launch_bounds__(64) void k_prepw(PrepArgs pa) {
    int r = blockIdx.x;                 // 0..1535
    int pq = r / 768, col = r % 768;
    int dir = col / 384, within = col % 384, gate = within / 128;
    int idx = pq * 2 + dir;             // {p_f,p_b,q_f,q_b}
    const float* wsrc = pa.wih[idx] + within * E_;
    __hip_bfloat16* dst = pq ? g_wq[col] : g_wp[col];
    for (int c = threadIdx.x; c < KP; c += 64)
        dst[c] = __float2bfloat16(c < E_ ? wsrc[c] : 0.f);
    if (threadIdx.x == 0) {
        float bsum = pa.bih[idx][within] + (gate < 2 ? pa.bhh[idx][within] : 0.f);
        (pq ? g_biasq : g_biasp)[col] = bsum;
        if (within >= 256) g_biasn[idx][within - 256] = pa.bhh[idx][within];
    }
}

// ---------------- whh -> MFMA B-fragment repack (bf16) ----------------
__global__ __launch_bounds__(512) void k_prepw2(const float* w0, const float* w1,
                                               const float* w2, const float* w3) {
    int widx = blockIdx.x;              // 0..3
    const float* whh = widx == 0 ? w0 : widx == 1 ? w1 : widx == 2 ? w2 : w3;
    int tid = threadIdx.x, l = tid & 63, w = tid >> 6;
    int l15 = l & 15, lg = l >> 4;
    int j = w * 16 + l15;
    #pragma unroll
    for (int f = 0; f < 12; f++) {
        int g = f >> 2, ks = f & 3;
        const float* src = whh + (long)(g * 128 + j) * HH_ + ks * 32 + lg * 8;
        bf16x8 v;
        #pragma unroll
        for (int e = 0; e < 8; e++) {
            unsigned u = __float_as_uint(src[e]);
            u = (u + 0x7FFFu + ((u >> 16) & 1u)) >> 16;   // RNE f32->bf16
            v[e] = (short)u;
        }
        ((bf16x8*)g_whhrep)[(widx * 12 + f) * 512 + tid] = v;
    }
}

// ---------------- embedding gather (f32 -> bf16, K padded) ----------------
__global__ __launch_bounds__(256) void k_gather(const int* pass, const int* ques, const float* emb) {
    int row = blockIdx.x * 4 + (threadIdx.x >> 6);
    int lane = threadIdx.x & 63;
    const int* tsrc; __hip_bfloat16* dst; int r;
    if (row < BP) { r = row; tsrc = pass; dst = &g_ep[r][0]; }
    else          { r = row - BP; tsrc = ques; dst = &g_eq[r][0]; }
    int tk = tsrc[r];
    const float* src = emb + (long)tk * E_;
    #pragma unroll
    for (int i = 0; i < 5; i++) {
        int c = i * 64 + lane;
        float v = (c < E_) ? src[c] : 0.f;
        dst[c] = __float2bfloat16(v);
    }
}

// ---------------- input-projection GEMM: x_t[dir][t][b][384] = ep @ wih^T + bias ----------------
__global__ __launch_bounds__(256) void k_gemm(int isQ) {
    const __hip_bfloat16* A  = isQ ? &g_eq[0][0] : &g_ep[0][0];
    const __hip_bfloat16* Bw = isQ ? &g_wq[0][0] : &g_wp[0][0];
    const float* bias = isQ ? g_biasq : g_biasp;
    float* Xt = isQ ? g_xtq : g_xtp;
    const int T = isQ ? Q_ : P_;
    const int tsh = isQ ? 6 : 9;        // log2(T)
    __shared__ __hip_bfloat16 As[128][40];
    __shared__ __hip_bfloat16 Bs[128][40];
    int m0 = blockIdx.x * 128, n0 = blockIdx.y * 128;
    int tid = threadIdx.x, lane = tid & 63, w = tid >> 6;
    int wm = (w & 1) * 64, wn = (w >> 1) * 64;
    f32x4 acc[4][4] = {};
    int lr = tid >> 1, lc = (tid & 1) * 16;
    for (int kt = 0; kt < KP; kt += 32) {
        *(bf16x8*)&As[lr][lc]   = *(const bf16x8*)&A [(m0 + lr) * KP + kt + lc];
        *(bf16x8*)&As[lr][lc+8] = *(const bf16x8*)&A [(m0 + lr) * KP + kt + lc + 8];
        *(bf16x8*)&Bs[lr][lc]   = *(const bf16x8*)&Bw[(n0 + lr) * KP + kt + lc];
        *(bf16x8*)&Bs[lr][lc+8] = *(const bf16x8*)&Bw[(n0 + lr) * KP + kt + lc + 8];
        __syncthreads();
        int kb = (lane >> 4) * 8, l15 = lane & 15;
        bf16x8 af[4], bfr[4];
        #pragma unroll
        for (int i = 0; i < 4; i++) af[i]  = *(bf16x8*)&As[wm + i*16 + l15][kb];
        #pragma unroll
        for (int j = 0; j < 4; j++) bfr[j] = *(bf16x8*)&Bs[wn + j*16 + l15][kb];
        #pragma unroll
        for (int i = 0; i < 4; i++)
            #pragma unroll
            for (int j = 0; j < 4; j++)
                acc[i][j] = __builtin_amdgcn_mfma_f32_16x16x32_bf16(af[i], bfr[j], acc[i][j], 0, 0, 0);
        __syncthreads();
    }
    int l15 = lane & 15, lr4 = (lane >> 4) * 4;
    #pragma unroll
    for (int jj = 0; jj < 4; jj++) {
        int n = n0 + wn + jj * 16 + l15;
        float bn = bias[n];
        int dirn = n >= 384;
        int col = n - dirn * 384;
        float* Cx = Xt + (long)dirn * T * B_ * 384;
        #pragma unroll
        for (int i = 0; i < 4; i++) {
            int mb = m0 + wm + i * 16 + lr4;
            #pragma unroll
            for (int q = 0; q < 4; q++) {
                int m = mb + q;
                int b = m >> tsh, t = m & (T - 1);
                Cx[((long)t * B_ + b) * 384 + col] = acc[i][jj][q] + bn;
            }
        }
    }
}

// ---------------- z-gate poison for masked steps (freeze h exactly) ----------------
__global__ __launch_bounds__(128) void k_maskz(const int* pass, const int* ques) {
    int row = blockIdx.x;
    int tid = threadIdx.x;
    int isQ = row >= BP;
    int rr = isQ ? row - BP : row;
    int tkn = isQ ? ques[rr] : pass[rr];
    if (tkn != 0) return;
    int T = isQ ? Q_ : P_;
    int b = rr / T, t = rr % T;
    float* xt = isQ ? g_xtq : g_xtp;
    xt[((long)0 * T * B_ + (long)t * B_ + b) * 384 + 128 + tid] = 1e9f;
    xt[((long)1 * T * B_ + (long)t * B_ + b) * 384 + 128 + tid] = 1e9f;
}

// ---------------- GRU recurrence: 4 blocks, 2-way chain interleave ----------------
// Block = one weight set {p_f,p_b,q_f,q_b}; 32 chains as two independent M=16
// sets A (batches 0-15) and B (16-31) sharing the resident weight fragments.
// Set B's issue fills set A's LDS/MFMA/trans latency; one barrier per pair.
// All addressing strength-reduced: running int offsets + precomputed swizzles.
#define GRU_SET_GATES(S, BUFBASE)                                              \
    { char* wb = hb + (BUFBASE);                                               \
      float* op = outp + ooff##S;                                              \
      _Pragma("unroll")                                                        \
      for (int q = 0; q < 4; q++) {                                            \
        float rg = __builtin_amdgcn_rcpf(1.f + __expf(-(a##S##0[q] + xar##S[q])));\
        float zg = __builtin_amdgcn_rcpf(1.f + __expf(-(a##S##1[q] + xaz##S[q])));\
        float ta = __builtin_amdgcn_fmed3f(fmaf(rg, a##S##2[q] + bnn, xan##S[q]), -15.f, 15.f);\
        float e2 = __expf(2.f * ta);                                           \
        float th = fmaf(-2.f, __builtin_amdgcn_rcpf(e2 + 1.f), 1.f);           \
        float hv = fmaf(zg, hold##S[q] - th, th);                              \
        hold##S[q] = hv;                                                       \
        *(__hip_bfloat16*)(wb + ((vw ^ (q << 4)) + q * 256)) = __float2bfloat16(hv);\
        op[q * TH] = hv;                                                       \
      } }

#define GRU_FULL(PAR, ST)                                                      \
  {                                                                            \
    f32x4 nrA, nzA, nnA, nrB, nzB, nnB;                                        \
    { const float* p0 = xt + xoff0A; const float* p1 = xt + xoff1A;            \
      nrA[0]=p0[0];   nrA[1]=p0[384]; nrA[2]=p1[0];   nrA[3]=p1[384];          \
      nzA[0]=p0[128]; nzA[1]=p0[512]; nzA[2]=p1[128]; nzA[3]=p1[512];          \
      nnA[0]=p0[256]; nnA[1]=p0[640]; nnA[2]=p1[256]; nnA[3]=p1[640]; }        \
    { const float* p0 = xt + xoff0B; const float* p1 = xt + xoff1B;            \
      nrB[0]=p0[0];   nrB[1]=p0[384]; nrB[2]=p1[0];   nrB[3]=p1[384];          \
      nzB[0]=p0[128]; nzB[1]=p0[512]; nzB[2]=p1[128]; nzB[3]=p1[512];          \
      nnB[0]=p0[256]; nnB[1]=p0[640]; nnB[2]=p1[256]; nnB[3]=p1[640]; }        \
    f32x4 aA0={0.f,0.f,0.f,0.f}, aA1=aA0, aA2=aA0, aB0=aA0, aB1=aA0, aB2=aA0;  \
    aA0 = __builtin_amdgcn_mfma_f32_16x16x32_bf16(afA0, b00, aA0, 0, 0, 0);    \
    aA1 = __builtin_amdgcn_mfma_f32_16x16x32_bf16(afA0, b10, aA1, 0, 0, 0);    \
    aA2 = __builtin_amdgcn_mfma_f32_16x16x32_bf16(afA0, b20, aA2, 0, 0, 0);    \
    aA0 = __builtin_amdgcn_mfma_f32_16x16x32_bf16(afA1, b01, aA0, 0, 0, 0);    \
    aA1 = __builtin_amdgcn_mfma_f32_16x16x32_bf16(afA1, b11, aA1, 0, 0, 0);    \
    aA2 = __builtin_amdgcn_mfma_f32_16x16x32_bf16(afA1, b21, aA2, 0, 0, 0);    \
    aA0 = __builtin_amdgcn_mfma_f32_16x16x32_bf16(afA2, b02, aA0, 0, 0, 0);    \
    aA1 = __builtin_amdgcn_mfma_f32_16x16x32_bf16(afA2, b12, aA1, 0, 0, 0);    \
    aA2 = __builtin_amdgcn_mfma_f32_16x16x32_bf16(afA2, b22, aA2, 0, 0, 0);    \
    aA0 = __builtin_amdgcn_mfma_f32_16x16x32_bf16(afA3, b03, aA0, 0, 0, 0);    \
    aA1 = __builtin_amdgcn_mfma_f32_16x16x32_bf16(afA3, b13, aA1, 0, 0, 0);    \
    aA2 = __builtin_amdgcn_mfma_f32_16x16x32_bf16(afA3, b23, aA2, 0, 0, 0);    \
    aB0 = __builtin_amdgcn_mfma_f32_16x16x32_bf16(afB0, b00, aB0, 0, 0, 0);    \
    aB1 = __builtin_amdgcn_mfma_f32_16x16x32_bf16(afB0, b10, aB1, 0, 0, 0);    \
    aB2 = __builtin_amdgcn_mfma_f32_16x16x32_bf16(afB0, b20, aB2, 0, 0, 0);    \
    aB0 = __builtin_amdgcn_mfma_f32_16x16x32_bf16(afB1, b01, aB0, 0, 0, 0);    \
    aB1 = __builtin_amdgcn_mfma_f32_16x16x32_bf16(afB1, b11, aB1, 0, 0, 0);    \
    aB2 = __builtin_amdgcn_mfma_f32_16x16x32_bf16(afB1, b21, aB2, 0, 0, 0);    \
    aB0 = __builtin_amdgcn_mfma_f32_16x16x32_bf16(afB2, b02, aB0, 0, 0, 0);    \
    aB1 = __builtin_amdgcn_mfma_f32_16x16x32_bf16(afB2, b12, aB1, 0, 0, 0);    \
    aB2 = __builtin_amdgcn_mfma_f32_16x16x32_bf16(afB2, b22, aB2, 0, 0, 0);    \
    aB0 = __builtin_amdgcn_mfma_f32_16x16x32_bf16(afB3, b03, aB0, 0, 0, 0);    \
    aB1 = __builtin_amdgcn_mfma_f32_16x16x32_bf16(afB3, b13, aB1, 0, 0, 0);    \
    aB2 = __builtin_amdgcn_mfma_f32_16x16x32_bf16(afB3, b23, aB2, 0, 0, 0);    \
    GRU_SET_GATES(A, (PAR) * 4096)                                             \
    GRU_SET_GATES(B, (2 + (PAR)) * 4096)                                       \
    asm volatile("s_waitcnt lgkmcnt(0)\n\ts_barrier" ::: "memory");            \
    { const char* rb = hb + (PAR) * 4096;                                      \
      afA0 = *(const bf16x8*)(rb + vr0); afA1 = *(const bf16x8*)(rb + vr1);    \
      afA2 = *(const bf16x8*)(rb + vr2); afA3 = *(const bf16x8*)(rb + vr3); }  \
    { const char* rb = hb + (2 + (PAR)) * 4096;                                \
      afB0 = *(const bf16x8*)(rb + vr0); afB1 = *(const bf16x8*)(rb + vr1);    \
      afB2 = *(const bf16x8*)(rb + vr2); afB3 = *(const bf16x8*)(rb + vr3); }  \
    xarA = nrA; xazA = nzA; xanA = nnA;                                        \
    xarB = nrB; xazB = nzB; xanB = nnB;                                        \
    { int adv = ((ST) + 2 < T) ? sdx : 0;                                      \
      xoff0A += adv; xoff1A += adv; xoff0B += adv; xoff1B += adv; }            \
    ooffA += sdo; ooffB += sdo;                                                \
  }

__global__ __launch_bounds__(512, 2) void k_gru() {
    int widx = blockIdx.x;              // 0..3 = p_f, p_b, q_f, q_b
    int isQ = widx >> 1, dir = widx & 1;
    const int T = isQ ? Q_ : P_;
    const float* xt = (isQ ? g_xtq : g_xtp) + (long)dir * T * B_ * 384;
    float* outp = isQ ? g_qenc : g_penc;
    const int TH = T * H_;
    int tid = threadIdx.x, l = tid & 63, w = tid >> 6;
    int l15 = l & 15, lg = l >> 4;
    int j = w * 16 + l15, m0 = lg * 4;

    const bf16x8* wrp = (const bf16x8*)g_whhrep + (long)widx * 12 * 512 + tid;
    bf16x8 b00 = wrp[0*512],  b01 = wrp[1*512],  b02 = wrp[2*512],  b03 = wrp[3*512];
    bf16x8 b10 = wrp[4*512],  b11 = wrp[5*512],  b12 = wrp[6*512],  b13 = wrp[7*512];
    bf16x8 b20 = wrp[8*512],  b21 = wrp[9*512],  b22 = wrp[10*512], b23 = wrp[11*512];
    float bnn = g_biasn[widx][j];

    __shared__ __align__(16) char hb[16384];   // 4 buffers: A-par0, A-par1, B-par0, B-par1

    // precomputed LDS swizzle addresses (byte offsets)
    int smz = (m0 & 7) << 4;
    int vw  = m0 * 256 + ((j * 2) ^ smz);                       // write base (q=0)
    int sw  = (l15 & 7) << 4;
    int vr0 = l15 * 256 + (((0*64) + lg * 16) ^ sw);
    int vr1 = l15 * 256 + (((1*64) + lg * 16) ^ sw);
    int vr2 = l15 * 256 + (((2*64) + lg * 16) ^ sw);
    int vr3 = l15 * 256 + (((3*64) + lg * 16) ^ sw);

    int sdx = dir ? -(B_ * 384) : (B_ * 384);
    int sdo = dir ? -H_ : H_;
    int t0 = dir ? T - 1 : 0;

    f32x4 holdA = {0.f,0.f,0.f,0.f}, holdB = holdA;
    bf16x8 z8 = {0,0,0,0,0,0,0,0};
    bf16x8 afA0 = z8, afA1 = z8, afA2 = z8, afA3 = z8;
    bf16x8 afB0 = z8, afB1 = z8, afB2 = z8, afB3 = z8;

    int xoff0A = (t0 * B_ + m0) * 384 + j;
    int xoff1A = xoff0A + 768;
    int xoff0B = (t0 * B_ + 16 + m0) * 384 + j;
    int xoff1B = xoff0B + 768;
    int ooffA = (m0 * T + t0) * H_ + dir * HH_ + j;
    int ooffB = ((16 + m0) * T + t0) * H_ + dir * HH_ + j;

    f32x4 xarA, xazA, xanA, xarB, xazB, xanB;
    { const float* p0 = xt + xoff0A; const float* p1 = xt + xoff1A;
      xarA[0]=p0[0];   xarA[1]=p0[384]; xarA[2]=p1[0];   xarA[3]=p1[384];
      xazA[0]=p0[128]; xazA[1]=p0[512]; xazA[2]=p1[128]; xazA[3]=p1[512];
      xanA[0]=p0[256]; xanA[1]=p0[640]; xanA[2]=p1[256]; xanA[3]=p1[640]; }
    { const float* p0 = xt + xoff0B; const float* p1 = xt + xoff1B;
      xarB[0]=p0[0];   xarB[1]=p0[384]; xarB[2]=p1[0];   xarB[3]=p1[384];
      xazB[0]=p0[128]; xazB[1]=p0[512]; xazB[2]=p1[128]; xazB[3]=p1[512];
      xanB[0]=p0[256]; xanB[1]=p0[640]; xanB[2]=p1[256]; xanB[3]=p1[640]; }
    xoff0A += sdx; xoff1A += sdx; xoff0B += sdx; xoff1B += sdx;

    for (int st = 0; st < T; st += 2) {
        GRU_FULL(0, st)
        GRU_FULL(1, st + 1)
    }
}

// ---------------- fused attention + output heads ----------------
#define QPAD 260
__global__ __launch_bounds__(256) void k_attn(const int* pass, const int* ques,
        const float* attn_w, const float* attn_b, const float* start_w,
        const float* start_b, const float* end_w, const float* end_b, float* out) {
    __shared__ float qs[Q_][QPAD];
    __shared__ float pw3[H_];
    __shared__ float lrow[Q_];
    __shared__ float probs[Q_];
    __shared__ float s2v[Q_];
    __shared__ int   qmS[Q_];
    __shared__ float red[4], redA[4], redB[4];
    __shared__ float awpart[4][QPAD];
    int b = blockIdx.x >> 6, pch = blockIdx.x & 63;
    int tid = threadIdx.x, lane = tid & 63, wid = tid >> 6;
    for (int i = tid; i < Q_ * H_; i += 256) {
        int q = i >> 8, h = i & 255;
        qs[q][h] = g_qenc[(long)(b * Q_ + q) * H_ + h];
    }
    if (tid < Q_) qmS[tid] = (ques[b * Q_ + tid] != 0);
    __syncthreads();
    int q4 = tid >> 2, part = tid & 3;
    {   // s2[q] = dot(qenc[q], w2)
        float p2 = 0.f;
        #pragma unroll 8
        for (int i = 0; i < 64; i++)
            p2 += qs[q4][part * 64 + i] * attn_w[256 + part * 64 + i];
        p2 += __shfl_xor(p2, 1);
        p2 += __shfl_xor(p2, 2);
        if (part == 0) s2v[q4] = p2;
    }
    __syncthreads();
    float ab = attn_b[0], sb = start_b[0], ebv = end_b[0];
    for (int pi = 0; pi < 8; pi++) {
        int p = pch * 8 + pi;
        float pv = g_penc[(long)(b * P_ + p) * H_ + tid];
        pw3[tid] = pv * attn_w[512 + tid];
        float r1 = pv * attn_w[tid];
        #pragma unroll
        for (int s = 1; s < 64; s <<= 1) r1 += __shfl_xor(r1, s);
        if (lane == 0) red[wid] = r1;
        __syncthreads();                                  // (A) pw3 + red
        float s1 = red[0] + red[1] + red[2] + red[3];
        float acc = 0.f;
        #pragma unroll
        for (int i = 0; i < 16; i++) {
            float4 qv = *(const float4*)&qs[q4][part * 64 + i * 4];
            float4 wv = *(const float4*)&pw3[part * 64 + i * 4];
            acc += qv.x * wv.x + qv.y * wv.y + qv.z * wv.z + qv.w * wv.w;
        }
        acc += __shfl_xor(acc, 1);
        acc += __shfl_xor(acc, 2);
        if (part == 0) lrow[q4] = qmS[q4] ? (s1 + s2v[q4] + acc + ab) : NEG;
        __syncthreads();                                  // (B) lrow
        if (tid < 64) {
            float v = lrow[tid];
            float m = v;
            #pragma unroll
            for (int s = 1; s < 64; s <<= 1) m = fmaxf(m, __shfl_xor(m, s));
            float e = __expf(v - m);
            float ss = e;
            #pragma unroll
            for (int s = 1; s < 64; s <<= 1) ss += __shfl_xor(ss, s);
            probs[tid] = e / ss;
        }
        __syncthreads();                                  // (C) probs
        float4 aw4 = {0.f, 0.f, 0.f, 0.f};
        #pragma unroll
        for (int qq = 0; qq < 16; qq++) {
            int q = wid * 16 + qq;
            float pq = probs[q];
            float4 qv = *(const float4*)&qs[q][lane * 4];
            aw4.x = fmaf(pq, qv.x, aw4.x);
            aw4.y = fmaf(pq, qv.y, aw4.y);
            aw4.z = fmaf(pq, qv.z, aw4.z);
            aw4.w = fmaf(pq, qv.w, aw4.w);
        }
        *(float4*)&awpart[wid][lane * 4] = aw4;
        __syncthreads();                                  // (D0) awpart
        float aw = awpart[0][tid] + awpart[1][tid] + awpart[2][tid] + awpart[3][tid];
        float spv = pv * start_w[tid] + aw * start_w[256 + tid] + pv * aw * start_w[512 + tid];
        float epv = pv * end_w[tid]   + aw * end_w[256 + tid]   + pv * aw * end_w[512 + tid];
        #pragma unroll
        for (int s = 1; s < 64; s <<= 1) {
            spv += __shfl_xor(spv, s);
            epv += __shfl_xor(epv, s);
        }
        if (lane == 0) { redA[wid] = spv; redB[wid] = epv; }
        __syncthreads();                                  // (D) redA/B
        if (tid == 0) {
            int pm = (pass[b * P_ + p] != 0);
            float sv = redA[0] + redA[1] + redA[2] + redA[3] + sb;
            float ev = redB[0] + redB[1] + redB[2] + redB[3] + ebv;
            out[b * P_ + p]       = pm ? sv : NEG;
            out[BP + b * P_ + p]  = pm ? ev : NEG;
        }
        __syncthreads();                                  // (E) end of row
    }
}

// ---------------- log_softmax over P per (batch, start/end) ----------------
__global__ __launch_bounds__(256) void k_lsm(float* out) {
    int b = blockIdx.x >> 1, which = blockIdx.x & 1;
    const float* src = out + which * BP + b * P_;
    int tid = threadIdx.x;
    float v0 = src[tid], v1 = src[tid + 256];
    __shared__ float red[4];
    float m = fmaxf(v0, v1);
    #pragma unroll
    for (int s = 1; s < 64; s <<= 1) m = fmaxf(m, __shfl_xor(m, s));
    if ((tid & 63) == 0) red[tid >> 6] = m;
    __syncthreads();
    m = fmaxf(fmaxf(red[0], red[1]), fmaxf(red[2], red[3]));
    __syncthreads();
    float ss = __expf(v0 - m) + __expf(v1 - m);
    #pragma unroll
    for (int s = 1; s < 64; s <<= 1) ss += __shfl_xor(ss, s);
    if ((tid & 63) == 0) red[tid >> 6] = ss;
    __syncthreads();
    float lse = m + logf(red[0] + red[1] + red[2] + red[3]);
    float* dst = out + (2 + which) * BP + b * P_;
    dst[tid] = v0 - lse;
    dst[tid + 256] = v1 - lse;
}

extern "C" void kernel_launch(void* const* d_in, const int* in_sizes, int n_in,
                              void* d_out, int out_size, void* d_ws, size_t ws_size,
                              hipStream_t stream) {
    const int* pass = (const int*)d_in[0];
    const int* ques = (const int*)d_in[1];
    const float* emb = (const float*)d_in[2];
    PrepArgs pa;
    const float* whh[4];
    const int base[4] = {3, 7, 11, 15};   // p_f, p_b, q_f, q_b blocks of 4 inputs
    for (int i = 0; i < 4; i++) {
        pa.wih[i] = (const float*)d_in[base[i] + 0];
        whh[i]    = (const float*)d_in[base[i] + 1];
        pa.bih[i] = (const float*)d_in[base[i] + 2];
        pa.bhh[i] = (const float*)d_in[base[i] + 3];
    }
    const float* attn_w  = (const float*)d_in[19];
    const float* attn_b  = (const float*)d_in[20];
    const float* start_w = (const float*)d_in[21];
    const float* start_b = (const float*)d_in[22];
    const float* end_w   = (const float*)d_in[23];
    const float* end_b   = (const float*)d_in[24];
    float* out = (float*)d_out;

    k_prepw <<<dim3(1536), dim3(64), 0, stream>>>(pa);
    k_prepw2<<<dim3(4), dim3(512), 0, stream>>>(whh[0], whh[1], whh[2], whh[3]);
    k_gather<<<dim3((BP + BQ) / 4), dim3(256), 0, stream>>>(pass, ques, emb);
    k_gemm  <<<dim3(BP / 128, 6), dim3(256), 0, stream>>>(0);
    k_gemm  <<<dim3(BQ / 128, 6), dim3(256), 0, stream>>>(1);
    k_maskz <<<dim3(BP + BQ), dim3(128), 0, stream>>>(pass, ques);
    k_gru   <<<dim3(4), dim3(512), 0, stream>>>();
    k_attn  <<<dim3(B_ * 64), dim3(256), 0, stream>>>(pass, ques, attn_w, attn_b,
                                                      start_w, start_b, end_w, end_b, out);
    k_lsm   <<<dim3(64), dim3(256), 0, stream>>>(out);
}

// Round 7
// 741.526 us; speedup vs baseline: 1.4071x; 1.4071x over previous
//
#include <hip/hip_runtime.h>
#include <hip/hip_bf16.h>

#define B_ 32
#define P_ 512
#define Q_ 64
#define E_ 300
#define KP 320          // E padded to multiple of 32 for MFMA K-steps
#define H_ 256
#define HH_ 128
#define NEG (-1e7f)
#define BP (B_*P_)
#define BQ (B_*Q_)

typedef __attribute__((ext_vector_type(8))) short bf16x8;
typedef __attribute__((ext_vector_type(4))) float f32x4;

// ---- static device workspace (fully rewritten every call) ----
// Embeddings gathered T-MAJOR: row = t*32 + b (so GEMM M-tiles span consecutive b)
__device__ __hip_bfloat16 g_ep[BP][KP];
__device__ __hip_bfloat16 g_eq[BQ][KP];
__device__ __hip_bfloat16 g_wp[768][KP];     // combined passage wih
__device__ __hip_bfloat16 g_wq[768][KP];     // combined question wih
__device__ float g_biasp[768];               // bih (+ bhh for r,z gates)
__device__ float g_biasq[768];
__device__ float g_biasn[4][HH_];            // bhh n-gate bias per weight set
__device__ short g_whhrep[4*12*512*8];       // whh repacked in MFMA B-frag order
// x projections as bf16 tiles: [dir][t][g=chain-group][col 0..383][chain 0..15]
__device__ short g_xtp[2L*P_*2*384*16];
__device__ short g_xtq[2L*Q_*2*384*16];
__device__ float g_penc[BP*H_];              // BiGRU passage encodings (f32)
__device__ float g_qenc[BQ*H_];              // BiGRU question encodings

struct PrepArgs { const float* wih[4]; const float* bih[4]; const float* bhh[4]; };

__device__ __forceinline__ unsigned short f2bf(float f) {
    unsigned u = __float_as_uint(f);
    u = (u + 0x7FFFu + ((u >> 16) & 1u)) >> 16;   // RNE f32->bf16
    return (unsigned short)u;
}

// ---------------- weight repack + bias fold ----------------
__global__ __launch_bounds__(64) void k_prepw(PrepArgs pa) {
    int r = blockIdx.x;                 // 0..1535
    int pq = r / 768, col = r % 768;
    int dir = col / 384, within = col % 384, gate = within / 128;
    int idx = pq * 2 + dir;             // {p_f,p_b,q_f,q_b}
    const float* wsrc = pa.wih[idx] + within * E_;
    __hip_bfloat16* dst = pq ? g_wq[col] : g_wp[col];
    for (int c = threadIdx.x; c < KP; c += 64)
        dst[c] = __float2bfloat16(c < E_ ? wsrc[c] : 0.f);
    if (threadIdx.x == 0) {
        float bsum = pa.bih[idx][within] + (gate < 2 ? pa.bhh[idx][within] : 0.f);
        (pq ? g_biasq : g_biasp)[col] = bsum;
        if (within >= 256) g_biasn[idx][within - 256] = pa.bhh[idx][within];
    }
}

// ---------------- whh -> MFMA B-fragment repack (bf16) ----------------
__global__ __launch_bounds__(512) void k_prepw2(const float* w0, const float* w1,
                                               const float* w2, const float* w3) {
    int widx = blockIdx.x;              // 0..3
    const float* whh = widx == 0 ? w0 : widx == 1 ? w1 : widx == 2 ? w2 : w3;
    int tid = threadIdx.x, l = tid & 63, w = tid >> 6;
    int l15 = l & 15, lg = l >> 4;
    int j = w * 16 + l15;
    #pragma unroll
    for (int f = 0; f < 12; f++) {
        int g = f >> 2, ks = f & 3;
        const float* src = whh + (long)(g * 128 + j) * HH_ + ks * 32 + lg * 8;
        bf16x8 v;
        #pragma unroll
        for (int e = 0; e < 8; e++) v[e] = (short)f2bf(src[e]);
        ((bf16x8*)g_whhrep)[(widx * 12 + f) * 512 + tid] = v;
    }
}

// ---------------- embedding gather (T-MAJOR rows, f32 -> bf16) ----------------
__global__ __launch_bounds__(256) void k_gather(const int* pass, const int* ques, const float* emb) {
    int row = blockIdx.x * 4 + (threadIdx.x >> 6);
    int lane = threadIdx.x & 63;
    const int* tsrc; __hip_bfloat16* dst; int r, T;
    if (row < BP) { r = row; tsrc = pass; dst = &g_ep[r][0]; T = P_; }
    else          { r = row - BP; tsrc = ques; dst = &g_eq[r][0]; T = Q_; }
    int b = r & 31, t = r >> 5;         // t-major
    int tk = tsrc[b * T + t];
    const float* src = emb + (long)tk * E_;
    #pragma unroll
    for (int i = 0; i < 5; i++) {
        int c = i * 64 + lane;
        float v = (c < E_) ? src[c] : 0.f;
        dst[c] = __float2bfloat16(v);
    }
}

// ---------------- input-projection GEMM -> bf16 staged-tile layout ----------------
__global__ __launch_bounds__(256) void k_gemm(int isQ) {
    const __hip_bfloat16* A  = isQ ? &g_eq[0][0] : &g_ep[0][0];
    const __hip_bfloat16* Bw = isQ ? &g_wq[0][0] : &g_wp[0][0];
    const float* bias = isQ ? g_biasq : g_biasp;
    short* Xt = isQ ? g_xtq : g_xtp;
    const int T = isQ ? Q_ : P_;
    __shared__ __hip_bfloat16 As[128][40];
    __shared__ __hip_bfloat16 Bs[128][40];
    int m0 = blockIdx.x * 128, n0 = blockIdx.y * 128;
    int tid = threadIdx.x, lane = tid & 63, w = tid >> 6;
    int wm = (w & 1) * 64, wn = (w >> 1) * 64;
    f32x4 acc[4][4] = {};
    int lr = tid >> 1, lc = (tid & 1) * 16;
    for (int kt = 0; kt < KP; kt += 32) {
        *(bf16x8*)&As[lr][lc]   = *(const bf16x8*)&A [(m0 + lr) * KP + kt + lc];
        *(bf16x8*)&As[lr][lc+8] = *(const bf16x8*)&A [(m0 + lr) * KP + kt + lc + 8];
        *(bf16x8*)&Bs[lr][lc]   = *(const bf16x8*)&Bw[(n0 + lr) * KP + kt + lc];
        *(bf16x8*)&Bs[lr][lc+8] = *(const bf16x8*)&Bw[(n0 + lr) * KP + kt + lc + 8];
        __syncthreads();
        int kb = (lane >> 4) * 8, l15 = lane & 15;
        bf16x8 af[4], bfr[4];
        #pragma unroll
        for (int i = 0; i < 4; i++) af[i]  = *(bf16x8*)&As[wm + i*16 + l15][kb];
        #pragma unroll
        for (int j = 0; j < 4; j++) bfr[j] = *(bf16x8*)&Bs[wn + j*16 + l15][kb];
        #pragma unroll
        for (int i = 0; i < 4; i++)
            #pragma unroll
            for (int j = 0; j < 4; j++)
                acc[i][j] = __builtin_amdgcn_mfma_f32_16x16x32_bf16(af[i], bfr[j], acc[i][j], 0, 0, 0);
        __syncthreads();
    }
    int l15 = lane & 15, lr4 = (lane >> 4) * 4;
    #pragma unroll
    for (int jj = 0; jj < 4; jj++) {
        int n = n0 + wn + jj * 16 + l15;
        float bn = bias[n];
        int dirn = n >= 384;
        int col = n - dirn * 384;
        short* Cx = Xt + (long)dirn * T * 2 * 384 * 16;
        #pragma unroll
        for (int i = 0; i < 4; i++) {
            int mb = m0 + wm + i * 16 + lr4;     // mb%4==0 -> q=0..3 same t, b consec
            int t = mb >> 5, b = mb & 31;
            int g = b >> 4, bi = b & 15;
            unsigned u0 = (unsigned)f2bf(acc[i][jj][0] + bn) |
                          ((unsigned)f2bf(acc[i][jj][1] + bn) << 16);
            unsigned u1 = (unsigned)f2bf(acc[i][jj][2] + bn) |
                          ((unsigned)f2bf(acc[i][jj][3] + bn) << 16);
            uint2 pk = {u0, u1};
            *(uint2*)&Cx[((long)(t * 2 + g) * 384 + col) * 16 + bi] = pk;
        }
    }
}

// ---------------- z-gate poison for masked steps (freeze h exactly) ----------------
__global__ __launch_bounds__(128) void k_maskz(const int* pass, const int* ques) {
    int row = blockIdx.x;
    int tid = threadIdx.x;
    int isQ = row >= BP;
    int rr = isQ ? row - BP : row;
    int T = isQ ? Q_ : P_;
    int b = rr / T, t = rr % T;
    int tkn = isQ ? ques[rr] : pass[rr];
    if (tkn != 0) return;
    short* xt = isQ ? g_xtq : g_xtp;
    unsigned short big = f2bf(1e9f);
    int g = b >> 4, bi = b & 15;
    long base = ((long)(t * 2 + g) * 384 + 128 + tid) * 16 + bi;
    xt[base] = (short)big;
    xt[base + (long)T * 2 * 384 * 16] = (short)big;
}

// ---------------- GRU recurrence: LDS-staged x, counted vmcnt ----------------
// 8 blocks x 512 threads, 16 chains each. x tiles (12KB bf16) staged 2 steps
// ahead via global_load_lds (no dest VGPRs -> compiler cannot early-drain);
// barrier waits vmcnt(9) = stage(st+1) complete, never a full drain.
#define GLL(gp, lp) __builtin_amdgcn_global_load_lds( \
    (const __attribute__((address_space(1))) unsigned int*)(gp), \
    (__attribute__((address_space(3))) unsigned int*)(lp), 16, 0, 0)

__global__ __launch_bounds__(512, 1) void k_gru() {
    int blk = blockIdx.x;               // [isQ][dir][g]
    int isQ = blk >> 2, dir = (blk >> 1) & 1, g = blk & 1, bbase = g * 16;
    const int T = isQ ? Q_ : P_;
    const char* gx = (const char*)((isQ ? g_xtq : g_xtp) + (long)dir * T * 2 * 384 * 16);
    float* outp = isQ ? g_qenc : g_penc;
    int widx = isQ * 2 + dir;
    int tid = threadIdx.x, l = tid & 63, w = tid >> 6;
    int l15 = l & 15, lg = l >> 4;
    int j = w * 16 + l15, m0 = lg * 4;

    const bf16x8* wrp = (const bf16x8*)g_whhrep + (long)widx * 12 * 512 + tid;
    bf16x8 b00 = wrp[0*512],  b01 = wrp[1*512],  b02 = wrp[2*512],  b03 = wrp[3*512];
    bf16x8 b10 = wrp[4*512],  b11 = wrp[5*512],  b12 = wrp[6*512],  b13 = wrp[7*512];
    bf16x8 b20 = wrp[8*512],  b21 = wrp[9*512],  b22 = wrp[10*512], b23 = wrp[11*512];
    float bnn = g_biasn[widx][j];

    __shared__ __align__(16) char lds[3 * 12288 + 2 * 4096];
    char* hb0 = lds + 36864;
    char* hb1 = hb0 + 4096;

    // LDS swizzle addresses (validated rounds 4-6)
    int smz = (m0 & 7) << 4;
    int vw  = m0 * 256 + ((j * 2) ^ smz);
    int sw  = (l15 & 7) << 4;
    int vr0 = l15 * 256 + ((0 * 64 + lg * 16) ^ sw);
    int vr1 = l15 * 256 + ((1 * 64 + lg * 16) ^ sw);
    int vr2 = l15 * 256 + ((2 * 64 + lg * 16) ^ sw);
    int vr3 = l15 * 256 + ((3 * 64 + lg * 16) ^ sw);
    int xoff = j * 32 + m0 * 8;         // [col][chain] bf16 tile

    int t0 = dir ? T - 1 : 0;
    int t1 = dir ? T - 2 : 1;
    // prologue: stage tiles t0, t1
    {
        const char* gt0 = gx + (long)(t0 * 2 + g) * 12288;
        const char* gt1 = gx + (long)(t1 * 2 + g) * 12288;
        GLL(gt0 + tid * 16, lds + (w << 10));
        if (w < 4) GLL(gt0 + 8192 + tid * 16, lds + 8192 + (w << 10));
        GLL(gt1 + tid * 16, lds + 12288 + (w << 10));
        if (w < 4) GLL(gt1 + 8192 + tid * 16, lds + 12288 + 8192 + (w << 10));
    }
    asm volatile("s_waitcnt vmcnt(0) lgkmcnt(0)\n\ts_barrier" ::: "memory");

    f32x4 hold = {0.f, 0.f, 0.f, 0.f};
    bf16x8 z8 = {0,0,0,0,0,0,0,0};
    bf16x8 af0 = z8, af1 = z8, af2 = z8, af3 = z8;
    char* lx0 = lds;
    char* lx1 = lds + 12288;
    char* lx2 = lds + 24576;
    int sdo = dir ? -H_ : H_;
    int ooff = ((bbase + m0) * T + t0) * H_ + dir * HH_ + j;
    const int TH = T * H_;

    for (int st = 0; st < T; st++) {
        // stage tile st+2 (clamped) into lx2 (not read until st+2)
        int t2s = (st + 2 < T) ? st + 2 : T - 1;
        int t2 = dir ? T - 1 - t2s : t2s;
        {
            const char* gt = gx + (long)(t2 * 2 + g) * 12288;
            GLL(gt + tid * 16, lx2 + (w << 10));
            if (w < 4) GLL(gt + 8192 + tid * 16, lx2 + 8192 + (w << 10));
        }
        // x for this step from LDS (ready since last barrier's vmcnt)
        uint2 d0 = *(const uint2*)(lx0 + xoff);
        uint2 d1 = *(const uint2*)(lx0 + xoff + 4096);
        uint2 d2 = *(const uint2*)(lx0 + xoff + 8192);

        f32x4 acc0 = {0.f,0.f,0.f,0.f}, acc1 = acc0, acc2 = acc0;
        acc0 = __builtin_amdgcn_mfma_f32_16x16x32_bf16(af0, b00, acc0, 0, 0, 0);
        acc1 = __builtin_amdgcn_mfma_f32_16x16x32_bf16(af0, b10, acc1, 0, 0, 0);
        acc2 = __builtin_amdgcn_mfma_f32_16x16x32_bf16(af0, b20, acc2, 0, 0, 0);
        acc0 = __builtin_amdgcn_mfma_f32_16x16x32_bf16(af1, b01, acc0, 0, 0, 0);
        acc1 = __builtin_amdgcn_mfma_f32_16x16x32_bf16(af1, b11, acc1, 0, 0, 0);
        acc2 = __builtin_amdgcn_mfma_f32_16x16x32_bf16(af1, b21, acc2, 0, 0, 0);
        acc0 = __builtin_amdgcn_mfma_f32_16x16x32_bf16(af2, b02, acc0, 0, 0, 0);
        acc1 = __builtin_amdgcn_mfma_f32_16x16x32_bf16(af2, b12, acc1, 0, 0, 0);
        acc2 = __builtin_amdgcn_mfma_f32_16x16x32_bf16(af2, b22, acc2, 0, 0, 0);
        acc0 = __builtin_amdgcn_mfma_f32_16x16x32_bf16(af3, b03, acc0, 0, 0, 0);
        acc1 = __builtin_amdgcn_mfma_f32_16x16x32_bf16(af3, b13, acc1, 0, 0, 0);
        acc2 = __builtin_amdgcn_mfma_f32_16x16x32_bf16(af3, b23, acc2, 0, 0, 0);

        // unpack x (bf16 -> f32 via shift/mask)
        float xr_[4] = { __uint_as_float(d0.x << 16), __uint_as_float(d0.x & 0xFFFF0000u),
                         __uint_as_float(d0.y << 16), __uint_as_float(d0.y & 0xFFFF0000u) };
        float xz_[4] = { __uint_as_float(d1.x << 16), __uint_as_float(d1.x & 0xFFFF0000u),
                         __uint_as_float(d1.y << 16), __uint_as_float(d1.y & 0xFFFF0000u) };
        float xn_[4] = { __uint_as_float(d2.x << 16), __uint_as_float(d2.x & 0xFFFF0000u),
                         __uint_as_float(d2.y << 16), __uint_as_float(d2.y & 0xFFFF0000u) };

        char* hw = (st & 1) ? hb1 : hb0;
        float* orow = outp + ooff;
        f32x4 hnew;
        #pragma unroll
        for (int q = 0; q < 4; q++) {
            float rg = __builtin_amdgcn_rcpf(1.f + __expf(-(acc0[q] + xr_[q])));
            float zg = __builtin_amdgcn_rcpf(1.f + __expf(-(acc1[q] + xz_[q])));
            float ta = __builtin_amdgcn_fmed3f(fmaf(rg, acc2[q] + bnn, xn_[q]), -15.f, 15.f);
            float e2 = __expf(2.f * ta);
            float th = fmaf(-2.f, __builtin_amdgcn_rcpf(e2 + 1.f), 1.f);
            float hv = fmaf(zg, hold[q] - th, th);
            hnew[q] = hv;
            *(__hip_bfloat16*)(hw + ((vw ^ (q << 4)) + q * 256)) = __float2bfloat16(hv);
            orow[q * TH] = hv;
        }
        hold = hnew;

        // barrier: stage(st+1) complete (issued last step; 9 = 4+1+4 younger ops),
        // h ds_writes drained; stage(st+2) + out stores stay in flight.
        asm volatile("s_waitcnt vmcnt(9) lgkmcnt(0)\n\ts_barrier" ::: "memory");

        af0 = *(const bf16x8*)(hw + vr0);
        af1 = *(const bf16x8*)(hw + vr1);
        af2 = *(const bf16x8*)(hw + vr2);
        af3 = *(const bf16x8*)(hw + vr3);

        char* tmp = lx0; lx0 = lx1; lx1 = lx2; lx2 = tmp;
        ooff += sdo;
    }
}

// ---------------- fused attention + output heads ----------------
#define QPAD 260
__global__ __launch_bounds__(256) void k_attn(const int* pass, const int* ques,
        const float* attn_w, const float* attn_b, const float* start_w,
        const float* start_b, const float* end_w, const float* end_b, float* out) {
    __shared__ float qs[Q_][QPAD];
    __shared__ float pw3[H_];
    __shared__ float lrow[Q_];
    __shared__ float probs[Q_];
    __shared__ float s2v[Q_];
    __shared__ int   qmS[Q_];
    __shared__ float red[4], redA[4], redB[4];
    __shared__ float awpart[4][QPAD];
    int b = blockIdx.x >> 6, pch = blockIdx.x & 63;
    int tid = threadIdx.x, lane = tid & 63, wid = tid >> 6;
    for (int i = tid; i < Q_ * H_; i += 256) {
        int q = i >> 8, h = i & 255;
        qs[q][h] = g_qenc[(long)(b * Q_ + q) * H_ + h];
    }
    if (tid < Q_) qmS[tid] = (ques[b * Q_ + tid] != 0);
    __syncthreads();
    int q4 = tid >> 2, part = tid & 3;
    {   // s2[q] = dot(qenc[q], w2)
        float p2 = 0.f;
        #pragma unroll 8
        for (int i = 0; i < 64; i++)
            p2 += qs[q4][part * 64 + i] * attn_w[256 + part * 64 + i];
        p2 += __shfl_xor(p2, 1);
        p2 += __shfl_xor(p2, 2);
        if (part == 0) s2v[q4] = p2;
    }
    __syncthreads();
    float ab = attn_b[0], sb = start_b[0], ebv = end_b[0];
    for (int pi = 0; pi < 8; pi++) {
        int p = pch * 8 + pi;
        float pv = g_penc[(long)(b * P_ + p) * H_ + tid];
        pw3[tid] = pv * attn_w[512 + tid];
        float r1 = pv * attn_w[tid];
        #pragma unroll
        for (int s = 1; s < 64; s <<= 1) r1 += __shfl_xor(r1, s);
        if (lane == 0) red[wid] = r1;
        __syncthreads();                                  // (A) pw3 + red
        float s1 = red[0] + red[1] + red[2] + red[3];
        float acc = 0.f;
        #pragma unroll
        for (int i = 0; i < 16; i++) {
            float4 qv = *(const float4*)&qs[q4][part * 64 + i * 4];
            float4 wv = *(const float4*)&pw3[part * 64 + i * 4];
            acc += qv.x * wv.x + qv.y * wv.y + qv.z * wv.z + qv.w * wv.w;
        }
        acc += __shfl_xor(acc, 1);
        acc += __shfl_xor(acc, 2);
        if (part == 0) lrow[q4] = qmS[q4] ? (s1 + s2v[q4] + acc + ab) : NEG;
        __syncthreads();                                  // (B) lrow
        if (tid < 64) {
            float v = lrow[tid];
            float m = v;
            #pragma unroll
            for (int s = 1; s < 64; s <<= 1) m = fmaxf(m, __shfl_xor(m, s));
            float e = __expf(v - m);
            float ss = e;
            #pragma unroll
            for (int s = 1; s < 64; s <<= 1) ss += __shfl_xor(ss, s);
            probs[tid] = e / ss;
        }
        __syncthreads();                                  // (C) probs
        float4 aw4 = {0.f, 0.f, 0.f, 0.f};
        #pragma unroll
        for (int qq = 0; qq < 16; qq++) {
            int q = wid * 16 + qq;
            float pq = probs[q];
            float4 qv = *(const float4*)&qs[q][lane * 4];
            aw4.x = fmaf(pq, qv.x, aw4.x);
            aw4.y = fmaf(pq, qv.y, aw4.y);
            aw4.z = fmaf(pq, qv.z, aw4.z);
            aw4.w = fmaf(pq, qv.w, aw4.w);
        }
        *(float4*)&awpart[wid][lane * 4] = aw4;
        __syncthreads();                                  // (D0) awpart
        float aw = awpart[0][tid] + awpart[1][tid] + awpart[2][tid] + awpart[3][tid];
        float spv = pv * start_w[tid] + aw * start_w[256 + tid] + pv * aw * start_w[512 + tid];
        float epv = pv * end_w[tid]   + aw * end_w[256 + tid]   + pv * aw * end_w[512 + tid];
        #pragma unroll
        for (int s = 1; s < 64; s <<= 1) {
            spv += __shfl_xor(spv, s);
            epv += __shfl_xor(epv, s);
        }
        if (lane == 0) { redA[wid] = spv; redB[wid] = epv; }
        __syncthreads();                                  // (D) redA/B
        if (tid == 0) {
            int pm = (pass[b * P_ + p] != 0);
            float sv = redA[0] + redA[1] + redA[2] + redA[3] + sb;
            float ev = redB[0] + redB[1] + redB[2] + redB[3] + ebv;
            out[b * P_ + p]       = pm ? sv : NEG;
            out[BP + b * P_ + p]  = pm ? ev : NEG;
        }
        __syncthreads();                                  // (E) end of row
    }
}

// ---------------- log_softmax over P per (batch, start/end) ----------------
__global__ __launch_bounds__(256) void k_lsm(float* out) {
    int b = blockIdx.x >> 1, which = blockIdx.x & 1;
    const float* src = out + which * BP + b * P_;
    int tid = threadIdx.x;
    float v0 = src[tid], v1 = src[tid + 256];
    __shared__ float red[4];
    float m = fmaxf(v0, v1);
    #pragma unroll
    for (int s = 1; s < 64; s <<= 1) m = fmaxf(m, __shfl_xor(m, s));
    if ((tid & 63) == 0) red[tid >> 6] = m;
    __syncthreads();
    m = fmaxf(fmaxf(red[0], red[1]), fmaxf(red[2], red[3]));
    __syncthreads();
    float ss = __expf(v0 - m) + __expf(v1 - m);
    #pragma unroll
    for (int s = 1; s < 64; s <<= 1) ss += __shfl_xor(ss, s);
    if ((tid & 63) == 0) red[tid >> 6] = ss;
    __syncthreads();
    float lse = m + logf(red[0] + red[1] + red[2] + red[3]);
    float* dst = out + (2 + which) * BP + b * P_;
    dst[tid] = v0 - lse;
    dst[tid + 256] = v1 - lse;
}

extern "C" void kernel_launch(void* const* d_in, const int* in_sizes, int n_in,
                              void* d_out, int out_size, void* d_ws, size_t ws_size,
                              hipStream_t stream) {
    const int* pass = (const int*)d_in[0];
    const int* ques = (const int*)d_in[1];
    const float* emb = (const float*)d_in[2];
    PrepArgs pa;
    const float* whh[4];
    const int base[4] = {3, 7, 11, 15};   // p_f, p_b, q_f, q_b blocks of 4 inputs
    for (int i = 0; i < 4; i++) {
        pa.wih[i] = (const float*)d_in[base[i] + 0];
        whh[i]    = (const float*)d_in[base[i] + 1];
        pa.bih[i] = (const float*)d_in[base[i] + 2];
        pa.bhh[i] = (const float*)d_in[base[i] + 3];
    }
    const float* attn_w  = (const float*)d_in[19];
    const float* attn_b  = (const float*)d_in[20];
    const float* start_w = (const float*)d_in[21];
    const float* start_b = (const float*)d_in[22];
    const float* end_w   = (const float*)d_in[23];
    const float* end_b   = (const float*)d_in[24];
    float* out = (float*)d_out;

    k_prepw <<<dim3(1536), dim3(64), 0, stream>>>(pa);
    k_prepw2<<<dim3(4), dim3(512), 0, stream>>>(whh[0], whh[1], whh[2], whh[3]);
    k_gather<<<dim3((BP + BQ) / 4), dim3(256), 0, stream>>>(pass, ques, emb);
    k_gemm  <<<dim3(BP / 128, 6), dim3(256), 0, stream>>>(0);
    k_gemm  <<<dim3(BQ / 128, 6), dim3(256), 0, stream>>>(1);
    k_maskz <<<dim3(BP + BQ), dim3(128), 0, stream>>>(pass, ques);
    k_gru   <<<dim3(8), dim3(512), 0, stream>>>();
    k_attn  <<<dim3(B_ * 64), dim3(256), 0, stream>>>(pass, ques, attn_w, attn_b,
                                                      start_w, start_b, end_w, end_b, out);
    k_lsm   <<<dim3(64), dim3(256), 0, stream>>>(out);
}